// Round 1
// baseline (354.359 us; speedup 1.0000x reference)
//
#include <hip/hip_runtime.h>
#include <cstdint>
#include <cstddef>

#define HIDDEN 1024
#define BATCH 4
#define SEQ 4096
#define M_ROWS (BATCH * SEQ)   // 16384
#define K_DIM 1024
#define CHUNK 128
#define NCHUNK (SEQ / CHUNK)   // 32

typedef __bf16 bf16_t;
typedef __bf16 v8bf __attribute__((ext_vector_type(8)));
typedef float v4f __attribute__((ext_vector_type(4)));

__device__ __forceinline__ unsigned short f32_to_bf16(float f) {
  unsigned int u = __float_as_uint(f);
  u += 0x7fffu + ((u >> 16) & 1u);   // round-to-nearest-even
  return (unsigned short)(u >> 16);
}

// ---- Convert input X (fp32 -> bf16), 4 elems/thread ----
__global__ void convert_x_kernel(const float* __restrict__ X,
                                 unsigned short* __restrict__ Xb, int n4) {
  int i = blockIdx.x * blockDim.x + threadIdx.x;
  if (i >= n4) return;
  float4 f = ((const float4*)X)[i];
  ushort4 u;
  u.x = f32_to_bf16(f.x); u.y = f32_to_bf16(f.y);
  u.z = f32_to_bf16(f.z); u.w = f32_to_bf16(f.w);
  ((ushort4*)Xb)[i] = u;
}

// ---- Convert W0|W1|W2 (each [1024][1024] fp32) into Wb bf16 [3072][1024] ----
__global__ void convert_w_kernel(const float* __restrict__ W0,
                                 const float* __restrict__ W1,
                                 const float* __restrict__ W2,
                                 unsigned short* __restrict__ Wb) {
  int i = blockIdx.x * blockDim.x + threadIdx.x;  // over 786432 float4s (exact)
  int mat = i >> 18;                              // 262144 float4 per matrix
  int off = i & 0x3FFFF;
  const float* src = (mat == 0) ? W0 : (mat == 1) ? W1 : W2;
  float4 f = ((const float4*)src)[off];
  ushort4 u;
  u.x = f32_to_bf16(f.x); u.y = f32_to_bf16(f.y);
  u.z = f32_to_bf16(f.z); u.w = f32_to_bf16(f.w);
  ((ushort4*)Wb)[i] = u;
}

// ---- m97-style bf16 GEMM: C[m][n] = sum_k A[m][k]*B[n][k]
// A: [16384][1024] bf16, B: [3072][1024] bf16 (B^T layout),
// C split into three [16384][1024] fp32 matrices by n/1024.
// 128x128 tile, BK=32, block=256 (4 waves, 2x2 of 64x64), 16x16x32 MFMA.
__global__ __launch_bounds__(256) void gemm_bt_kernel(
    const bf16_t* __restrict__ A, const bf16_t* __restrict__ B,
    float* __restrict__ C0, float* __restrict__ C1, float* __restrict__ C2) {
  __shared__ bf16_t As[128 * 32];
  __shared__ bf16_t Bs[128 * 32];

  const int tid = threadIdx.x;
  const int wave = tid >> 6;
  const int lane = tid & 63;
  const int wr = wave >> 1;      // wave row (0..1) -> 64-row half
  const int wc = wave & 1;       // wave col (0..1) -> 64-col half
  const int mtile0 = blockIdx.y * 128;
  const int ntile0 = blockIdx.x * 128;

  const int quad = lane >> 4;    // 0..3
  const int r16 = lane & 15;

  v4f acc[4][4];
#pragma unroll
  for (int i = 0; i < 4; ++i)
#pragma unroll
    for (int j = 0; j < 4; ++j) acc[i][j] = (v4f)(0.0f);

  for (int k0 = 0; k0 < K_DIM; k0 += 32) {
    __syncthreads();  // previous iter's LDS readers done before overwrite
#pragma unroll
    for (int jj = 0; jj < 2; ++jj) {
      // chunk id: 512 x 16B chunks cover As (8 KiB); row m = cid>>2, k-chunk = cid&3
      int cid = wave * 128 + jj * 64 + lane;
      int m = cid >> 2;
      int kc = cid & 3;
      const bf16_t* gA = A + (size_t)(mtile0 + m) * K_DIM + k0 + kc * 8;
      const bf16_t* gB = B + (size_t)(ntile0 + m) * K_DIM + k0 + kc * 8;
      // LDS dest is wave-uniform base + lane*16 (hardware-imposed)
      __builtin_amdgcn_global_load_lds(
          (__attribute__((address_space(1))) void*)gA,
          (__attribute__((address_space(3))) void*)((char*)As + (wave * 2 + jj) * 1024),
          16, 0, 0);
      __builtin_amdgcn_global_load_lds(
          (__attribute__((address_space(1))) void*)gB,
          (__attribute__((address_space(3))) void*)((char*)Bs + (wave * 2 + jj) * 1024),
          16, 0, 0);
    }
    __syncthreads();  // compiler emits vmcnt(0) drain before s_barrier

    v8bf a[4], b[4];
#pragma unroll
    for (int i = 0; i < 4; ++i)
      a[i] = *(const v8bf*)&As[(wr * 64 + i * 16 + r16) * 32 + quad * 8];
#pragma unroll
    for (int j = 0; j < 4; ++j)
      b[j] = *(const v8bf*)&Bs[(wc * 64 + j * 16 + r16) * 32 + quad * 8];
#pragma unroll
    for (int i = 0; i < 4; ++i)
#pragma unroll
      for (int j = 0; j < 4; ++j)
        acc[i][j] = __builtin_amdgcn_mfma_f32_16x16x32_bf16(a[i], b[j], acc[i][j], 0, 0, 0);
  }

  // Epilogue: C/D layout col=lane&15, row=quad*4+reg (m89/m91-verified)
  const int mat = (int)blockIdx.x >> 3;
  float* Cm = (mat == 0) ? C0 : (mat == 1) ? C1 : C2;
  const int ncol0 = ((int)blockIdx.x & 7) * 128;
#pragma unroll
  for (int i = 0; i < 4; ++i) {
#pragma unroll
    for (int j = 0; j < 4; ++j) {
#pragma unroll
      for (int r = 0; r < 4; ++r) {
        int row = mtile0 + wr * 64 + i * 16 + quad * 4 + r;
        int col = ncol0 + wc * 64 + j * 16 + r16;
        Cm[(size_t)row * HIDDEN + col] = acc[i][j][r];
      }
    }
  }
}

// ---- Pass B: per-(b,ch) max of S=(C0+C1)/8 over 128-row chunks ----
// grid: (4 ch-tiles, 32 chunks, 4 batch), block 256
__global__ void chunkmax_kernel(const float* __restrict__ C0,
                                const float* __restrict__ C1,
                                float* __restrict__ cmax) {
  int ch = blockIdx.x * 256 + threadIdx.x;
  int chunk = blockIdx.y;
  int b = blockIdx.z;
  size_t base = ((size_t)b * SEQ + (size_t)chunk * CHUNK) * HIDDEN + ch;
  float m = -INFINITY;
#pragma unroll 4
  for (int s = 0; s < CHUNK; ++s) {
    float v = (C0[base] + C1[base]) * 0.125f;
    m = fmaxf(m, v);
    base += HIDDEN;
  }
  cmax[((size_t)b * NCHUNK + chunk) * HIDDEN + ch] = m;
}

// ---- Pass D: prefix from chunk maxes + in-chunk inclusive cummax + fuse ----
// out (== C1 buffer) is read (out1) then overwritten, same thread/element.
__global__ void final_kernel(const float* __restrict__ C0,
                             const float* __restrict__ C2,
                             const float* __restrict__ cmax,
                             float* __restrict__ out) {
  int ch = blockIdx.x * 256 + threadIdx.x;
  int chunk = blockIdx.y;
  int b = blockIdx.z;
  float run = -INFINITY;
  const float* cp = cmax + (size_t)b * NCHUNK * HIDDEN + ch;
  for (int j = 0; j < chunk; ++j) run = fmaxf(run, cp[(size_t)j * HIDDEN]);
  size_t base = ((size_t)b * SEQ + (size_t)chunk * CHUNK) * HIDDEN + ch;
#pragma unroll 4
  for (int s = 0; s < CHUNK; ++s) {
    float o1 = out[base];
    float v = (C0[base] + o1) * 0.125f;
    run = fmaxf(run, v);
    float o2 = C2[base];
    out[base] = (run + o2) * run + o1;
    base += HIDDEN;
  }
}

extern "C" void kernel_launch(void* const* d_in, const int* in_sizes, int n_in,
                              void* d_out, int out_size, void* d_ws, size_t ws_size,
                              hipStream_t stream) {
  const float* X = (const float*)d_in[0];
  const float* W0 = (const float*)d_in[1];
  const float* W1 = (const float*)d_in[2];
  const float* W2 = (const float*)d_in[3];
  float* out = (float*)d_out;

  // Workspace layout (166.5 MiB total):
  //   Xb   bf16 [16384][1024]   33,554,432 B
  //   Wb   bf16 [3072][1024]     6,291,456 B
  //   C0   fp32 [16384][1024]   67,108,864 B
  //   C2   fp32 [16384][1024]   67,108,864 B
  //   cmax fp32 [4][32][1024]      524,288 B
  char* ws = (char*)d_ws;
  unsigned short* Xb = (unsigned short*)ws;
  unsigned short* Wb = (unsigned short*)(ws + 33554432);
  float* C0 = (float*)(ws + 33554432 + 6291456);
  float* C2 = (float*)(ws + 33554432 + 6291456 + 67108864);
  float* cmax = (float*)(ws + 33554432 + 6291456 + 2 * 67108864);
  float* C1 = out;  // C1 lives in d_out; final pass reads then overwrites

  convert_x_kernel<<<16384, 256, 0, stream>>>(X, Xb, 4194304);
  convert_w_kernel<<<3072, 256, 0, stream>>>(W0, W1, W2, Wb);

  dim3 ggrid(24, 128);  // n-tiles x m-tiles
  gemm_bt_kernel<<<ggrid, 256, 0, stream>>>((const bf16_t*)Xb, (const bf16_t*)Wb,
                                            C0, C1, C2);

  dim3 sgrid(HIDDEN / 256, NCHUNK, BATCH);
  chunkmax_kernel<<<sgrid, 256, 0, stream>>>(C0, C1, cmax);
  final_kernel<<<sgrid, 256, 0, stream>>>(C0, C2, cmax, out);
}

// Round 2
// 311.060 us; speedup vs baseline: 1.1392x; 1.1392x over previous
//
#include <hip/hip_runtime.h>
#include <cstdint>
#include <cstddef>

#define HIDDEN 1024
#define BATCH 4
#define SEQ 4096
#define M_ROWS (BATCH * SEQ)   // 16384
#define K_DIM 1024
#define SUBCHUNK 32
#define NSUB (SEQ / SUBCHUNK)  // 128

typedef __bf16 bf16_t;
typedef __bf16 v8bf __attribute__((ext_vector_type(8)));
typedef float v4f __attribute__((ext_vector_type(4)));

__device__ __forceinline__ unsigned short f32_to_bf16(float f) {
  unsigned int u = __float_as_uint(f);
  u += 0x7fffu + ((u >> 16) & 1u);   // round-to-nearest-even
  return (unsigned short)(u >> 16);
}
__device__ __forceinline__ float bf16_to_f32(unsigned short u) {
  return __uint_as_float((unsigned int)u << 16);
}

// ---- Convert input X (fp32 -> bf16), 4 elems/thread ----
__global__ void convert_x_kernel(const float* __restrict__ X,
                                 unsigned short* __restrict__ Xb, int n4) {
  int i = blockIdx.x * blockDim.x + threadIdx.x;
  if (i >= n4) return;
  float4 f = ((const float4*)X)[i];
  ushort4 u;
  u.x = f32_to_bf16(f.x); u.y = f32_to_bf16(f.y);
  u.z = f32_to_bf16(f.z); u.w = f32_to_bf16(f.w);
  ((ushort4*)Xb)[i] = u;
}

// ---- Build Wb bf16 [3072][1024]:  Ws=(W0+W1)/8 | W1 | W2 ----
__global__ void convert_w_kernel(const float* __restrict__ W0,
                                 const float* __restrict__ W1,
                                 const float* __restrict__ W2,
                                 unsigned short* __restrict__ Wb) {
  int i = blockIdx.x * blockDim.x + threadIdx.x;  // over 786432 float4s (exact)
  int mat = i >> 18;                              // 262144 float4 per matrix
  int off = i & 0x3FFFF;
  float4 f;
  if (mat == 0) {
    float4 a = ((const float4*)W0)[off];
    float4 b = ((const float4*)W1)[off];
    f.x = (a.x + b.x) * 0.125f; f.y = (a.y + b.y) * 0.125f;
    f.z = (a.z + b.z) * 0.125f; f.w = (a.w + b.w) * 0.125f;
  } else {
    const float* src = (mat == 1) ? W1 : W2;
    f = ((const float4*)src)[off];
  }
  ushort4 u;
  u.x = f32_to_bf16(f.x); u.y = f32_to_bf16(f.y);
  u.z = f32_to_bf16(f.z); u.w = f32_to_bf16(f.w);
  ((ushort4*)Wb)[i] = u;
}

// ---- bf16 GEMM with swizzled LDS + fused sub-chunk max epilogue ----
// C[m][n] = sum_k A[m][k]*B[n][k];  A:[16384][1024], B:[3072][1024] (B^T layout)
// Outputs (bf16): S (n/1024==0), C1 (==1), C2 (==2).  mat-0 blocks also emit
// cmax[b][sub][col] = max over 32-row sub-chunks of S.
// 128x128 tile, BK=32, block=256 (4 waves, 2x2 of 64x64), 16x16x32 MFMA.
__global__ __launch_bounds__(256) void gemm_bt_kernel(
    const bf16_t* __restrict__ A, const bf16_t* __restrict__ B,
    unsigned short* __restrict__ Sp, unsigned short* __restrict__ C1p,
    unsigned short* __restrict__ C2p, float* __restrict__ cmax) {
  __shared__ bf16_t As[128 * 32];
  __shared__ bf16_t Bs[128 * 32];

  const int tid = threadIdx.x;
  const int wave = tid >> 6;
  const int lane = tid & 63;
  const int wr = wave >> 1;      // wave row (0..1) -> 64-row half
  const int wc = wave & 1;       // wave col (0..1) -> 64-col half
  const int mtile0 = blockIdx.y * 128;
  const int ntile0 = blockIdx.x * 128;

  const int quad = lane >> 4;    // 0..3
  const int r16 = lane & 15;
  // XOR swizzle: LDS chunk (m,kc) holds global k-chunk kc^((m>>1)&3).
  // Reader of (row, quad) finds it at kc_lds = quad ^ ((row>>1)&3); since
  // row = base16 + r16, (row>>1)&3 == (r16>>1)&3 -> lane-constant.
  const int sw = quad ^ ((r16 >> 1) & 3);

  v4f acc[4][4];
#pragma unroll
  for (int i = 0; i < 4; ++i)
#pragma unroll
    for (int j = 0; j < 4; ++j) acc[i][j] = (v4f)(0.0f);

  for (int k0 = 0; k0 < K_DIM; k0 += 32) {
    __syncthreads();  // previous iter's LDS readers done before overwrite
#pragma unroll
    for (int jj = 0; jj < 2; ++jj) {
      // 512 x 16B chunks cover As; LDS chunk cid = wave*128+jj*64+lane.
      int cid = wave * 128 + jj * 64 + lane;
      int m = cid >> 2;
      int kcg = (cid & 3) ^ ((cid >> 3) & 3);   // swizzled global k-chunk
      const bf16_t* gA = A + (size_t)(mtile0 + m) * K_DIM + k0 + kcg * 8;
      const bf16_t* gB = B + (size_t)(ntile0 + m) * K_DIM + k0 + kcg * 8;
      // LDS dest is wave-uniform base + lane*16 (hardware-imposed)
      __builtin_amdgcn_global_load_lds(
          (__attribute__((address_space(1))) void*)gA,
          (__attribute__((address_space(3))) void*)((char*)As + (wave * 2 + jj) * 1024),
          16, 0, 0);
      __builtin_amdgcn_global_load_lds(
          (__attribute__((address_space(1))) void*)gB,
          (__attribute__((address_space(3))) void*)((char*)Bs + (wave * 2 + jj) * 1024),
          16, 0, 0);
    }
    __syncthreads();  // compiler emits vmcnt(0) drain before s_barrier

    v8bf a[4], b[4];
#pragma unroll
    for (int i = 0; i < 4; ++i)
      a[i] = *(const v8bf*)&As[(wr * 64 + i * 16 + r16) * 32 + sw * 8];
#pragma unroll
    for (int j = 0; j < 4; ++j)
      b[j] = *(const v8bf*)&Bs[(wc * 64 + j * 16 + r16) * 32 + sw * 8];
#pragma unroll
    for (int i = 0; i < 4; ++i)
#pragma unroll
      for (int j = 0; j < 4; ++j)
        acc[i][j] = __builtin_amdgcn_mfma_f32_16x16x32_bf16(a[i], b[j], acc[i][j], 0, 0, 0);
  }

  // Epilogue: C/D layout col=lane&15, row=quad*4+reg (m89/m91-verified)
  const int mat = (int)blockIdx.x >> 3;
  unsigned short* Cm = (mat == 0) ? Sp : (mat == 1) ? C1p : C2p;
  const int ncol0 = ((int)blockIdx.x & 7) * 128;
#pragma unroll
  for (int i = 0; i < 4; ++i) {
#pragma unroll
    for (int j = 0; j < 4; ++j) {
#pragma unroll
      for (int r = 0; r < 4; ++r) {
        int row = mtile0 + wr * 64 + i * 16 + quad * 4 + r;
        int col = ncol0 + wc * 64 + j * 16 + r16;
        Cm[(size_t)row * HIDDEN + col] = f32_to_bf16(acc[i][j][r]);
      }
    }
  }

  if (mat == 0) {
    // 32-row sub-chunk maxes of S. Rows wr*64+ih*32..+32 live in i=ih*2..ih*2+1
    // across quads; reduce lane-local then across quads (lane bits 4,5).
    const int b = mtile0 >> 12;
    const int sub0 = (mtile0 & 4095) >> 5;
#pragma unroll
    for (int ih = 0; ih < 2; ++ih) {
#pragma unroll
      for (int j = 0; j < 4; ++j) {
        float v = -INFINITY;
#pragma unroll
        for (int ii = 0; ii < 2; ++ii)
#pragma unroll
          for (int r = 0; r < 4; ++r)
            v = fmaxf(v, acc[ih * 2 + ii][j][r]);
        v = fmaxf(v, __shfl_xor(v, 16));
        v = fmaxf(v, __shfl_xor(v, 32));
        if (quad == 0) {
          int sub = sub0 + wr * 2 + ih;
          int col = ncol0 + wc * 64 + j * 16 + r16;
          cmax[((size_t)b * NSUB + sub) * HIDDEN + col] = v;
        }
      }
    }
  }
}

// ---- Final: exclusive prefix-max from cmax + in-subchunk cummax + fuse ----
// grid (1, 128, 4), block 256; thread handles 4 consecutive cols.
__global__ void final_kernel(const unsigned short* __restrict__ S,
                             const unsigned short* __restrict__ C1,
                             const unsigned short* __restrict__ C2,
                             const float* __restrict__ cmax,
                             float* __restrict__ out) {
  const int col = threadIdx.x * 4;
  const int sub = blockIdx.y;
  const int b = blockIdx.z;
  float4 run = make_float4(-INFINITY, -INFINITY, -INFINITY, -INFINITY);
  const float* cp = cmax + (size_t)b * NSUB * HIDDEN + col;
  for (int j = 0; j < sub; ++j) {
    float4 c = *(const float4*)(cp + (size_t)j * HIDDEN);
    run.x = fmaxf(run.x, c.x); run.y = fmaxf(run.y, c.y);
    run.z = fmaxf(run.z, c.z); run.w = fmaxf(run.w, c.w);
  }
  size_t base = ((size_t)b * SEQ + (size_t)sub * SUBCHUNK) * HIDDEN + col;
#pragma unroll 4
  for (int s = 0; s < SUBCHUNK; ++s) {
    ushort4 us = *(const ushort4*)(S + base);
    run.x = fmaxf(run.x, bf16_to_f32(us.x));
    run.y = fmaxf(run.y, bf16_to_f32(us.y));
    run.z = fmaxf(run.z, bf16_to_f32(us.z));
    run.w = fmaxf(run.w, bf16_to_f32(us.w));
    ushort4 u1 = *(const ushort4*)(C1 + base);
    ushort4 u2 = *(const ushort4*)(C2 + base);
    float4 o;
    o.x = (run.x + bf16_to_f32(u2.x)) * run.x + bf16_to_f32(u1.x);
    o.y = (run.y + bf16_to_f32(u2.y)) * run.y + bf16_to_f32(u1.y);
    o.z = (run.z + bf16_to_f32(u2.z)) * run.z + bf16_to_f32(u1.z);
    o.w = (run.w + bf16_to_f32(u2.w)) * run.w + bf16_to_f32(u1.w);
    *(float4*)(out + base) = o;
    base += HIDDEN;
  }
}

extern "C" void kernel_launch(void* const* d_in, const int* in_sizes, int n_in,
                              void* d_out, int out_size, void* d_ws, size_t ws_size,
                              hipStream_t stream) {
  const float* X = (const float*)d_in[0];
  const float* W0 = (const float*)d_in[1];
  const float* W1 = (const float*)d_in[2];
  const float* W2 = (const float*)d_in[3];
  float* out = (float*)d_out;

  // Workspace layout (~142.6 MiB):
  //   Xb   bf16 [16384][1024]   33,554,432 B
  //   Wb   bf16 [3072][1024]     6,291,456 B
  //   Sp   bf16 [16384][1024]   33,554,432 B
  //   C1p  bf16 [16384][1024]   33,554,432 B
  //   C2p  bf16 [16384][1024]   33,554,432 B
  //   cmax fp32 [4][128][1024]   2,097,152 B
  char* ws = (char*)d_ws;
  unsigned short* Xb = (unsigned short*)ws;
  unsigned short* Wb = (unsigned short*)(ws + 33554432);
  unsigned short* Sp = (unsigned short*)(ws + 33554432 + 6291456);
  unsigned short* C1p = (unsigned short*)(ws + 2 * 33554432 + 6291456);
  unsigned short* C2p = (unsigned short*)(ws + 3 * 33554432 + 6291456);
  float* cmax = (float*)(ws + 4 * 33554432 + 6291456);

  convert_x_kernel<<<16384, 256, 0, stream>>>(X, Xb, 4194304);
  convert_w_kernel<<<3072, 256, 0, stream>>>(W0, W1, W2, Wb);

  dim3 ggrid(24, 128);  // n-tiles x m-tiles
  gemm_bt_kernel<<<ggrid, 256, 0, stream>>>((const bf16_t*)Xb, (const bf16_t*)Wb,
                                            Sp, C1p, C2p, cmax);

  dim3 fgrid(1, NSUB, BATCH);
  final_kernel<<<fgrid, 256, 0, stream>>>(Sp, C1p, C2p, cmax, out);
}

// Round 3
// 309.926 us; speedup vs baseline: 1.1434x; 1.0037x over previous
//
#include <hip/hip_runtime.h>
#include <cstdint>
#include <cstddef>

#define HIDDEN 1024
#define BATCH 4
#define SEQ 4096
#define M_ROWS (BATCH * SEQ)   // 16384
#define K_DIM 1024
#define SUBCHUNK 32
#define NSUB (SEQ / SUBCHUNK)  // 128

typedef __bf16 bf16_t;
typedef __bf16 v8bf __attribute__((ext_vector_type(8)));
typedef float v4f __attribute__((ext_vector_type(4)));

__device__ __forceinline__ unsigned short f32_to_bf16(float f) {
  unsigned int u = __float_as_uint(f);
  u += 0x7fffu + ((u >> 16) & 1u);   // round-to-nearest-even
  return (unsigned short)(u >> 16);
}
__device__ __forceinline__ float bf16_to_f32(unsigned short u) {
  return __uint_as_float((unsigned int)u << 16);
}

// ---- Merged convert: X fp32->bf16 (blocks 0..16383) and
//      Wb = (W0+W1)/8 | W1 | W2 as bf16 (blocks 16384..19455) ----
__global__ void convert_kernel(const float* __restrict__ X,
                               const float* __restrict__ W0,
                               const float* __restrict__ W1,
                               const float* __restrict__ W2,
                               unsigned short* __restrict__ Xb,
                               unsigned short* __restrict__ Wb) {
  int bx = blockIdx.x;
  if (bx < 16384) {
    int i = bx * 256 + threadIdx.x;        // over 4,194,304 float4s (exact)
    float4 f = ((const float4*)X)[i];
    ushort4 u;
    u.x = f32_to_bf16(f.x); u.y = f32_to_bf16(f.y);
    u.z = f32_to_bf16(f.z); u.w = f32_to_bf16(f.w);
    ((ushort4*)Xb)[i] = u;
  } else {
    int i = (bx - 16384) * 256 + threadIdx.x;  // over 786,432 float4s (exact)
    int mat = i >> 18;                          // 262,144 float4 per matrix
    int off = i & 0x3FFFF;
    float4 f;
    if (mat == 0) {
      float4 a = ((const float4*)W0)[off];
      float4 b = ((const float4*)W1)[off];
      f.x = (a.x + b.x) * 0.125f; f.y = (a.y + b.y) * 0.125f;
      f.z = (a.z + b.z) * 0.125f; f.w = (a.w + b.w) * 0.125f;
    } else {
      const float* src = (mat == 1) ? W1 : W2;
      f = ((const float4*)src)[off];
    }
    ushort4 u;
    u.x = f32_to_bf16(f.x); u.y = f32_to_bf16(f.y);
    u.z = f32_to_bf16(f.z); u.w = f32_to_bf16(f.w);
    ((ushort4*)Wb)[i] = u;
  }
}

// ---- bf16 GEMM, swizzled LDS, fused in-subchunk-cummax epilogue ----
// C[m][n] = sum_k A[m][k]*B[n][k];  A:[16384][1024], B:[3072][1024] (B^T).
// mat==0 blocks store L = inclusive 32-row cummax of S (bf16) + cmax (fp32
// subchunk totals); mat 1/2 store plain bf16 C1/C2.
// 128x128 tile, BK=32, block=256 (4 waves, 2x2 of 64x64), 16x16x32 MFMA.
__global__ __launch_bounds__(256) void gemm_bt_kernel(
    const bf16_t* __restrict__ A, const bf16_t* __restrict__ B,
    unsigned short* __restrict__ Lp, unsigned short* __restrict__ C1p,
    unsigned short* __restrict__ C2p, float* __restrict__ cmax) {
  __shared__ bf16_t As[128 * 32];
  __shared__ bf16_t Bs[128 * 32];

  const int tid = threadIdx.x;
  const int wave = tid >> 6;
  const int lane = tid & 63;
  const int wr = wave >> 1;      // wave row (0..1) -> 64-row half
  const int wc = wave & 1;       // wave col (0..1) -> 64-col half
  const int mtile0 = blockIdx.y * 128;
  const int ntile0 = blockIdx.x * 128;

  const int quad = lane >> 4;    // 0..3
  const int r16 = lane & 15;
  // XOR swizzle: LDS chunk (m,kc) holds global k-chunk kc^((m>>1)&3);
  // reader finds its chunk at quad^((r16>>1)&3)  (bank-conflict-free, R2: 0)
  const int sw = quad ^ ((r16 >> 1) & 3);

  v4f acc[4][4];
#pragma unroll
  for (int i = 0; i < 4; ++i)
#pragma unroll
    for (int j = 0; j < 4; ++j) acc[i][j] = (v4f)(0.0f);

  for (int k0 = 0; k0 < K_DIM; k0 += 32) {
    __syncthreads();  // previous iter's LDS readers done before overwrite
#pragma unroll
    for (int jj = 0; jj < 2; ++jj) {
      int cid = wave * 128 + jj * 64 + lane;
      int m = cid >> 2;
      int kcg = (cid & 3) ^ ((cid >> 3) & 3);   // swizzled global k-chunk
      const bf16_t* gA = A + (size_t)(mtile0 + m) * K_DIM + k0 + kcg * 8;
      const bf16_t* gB = B + (size_t)(ntile0 + m) * K_DIM + k0 + kcg * 8;
      __builtin_amdgcn_global_load_lds(
          (__attribute__((address_space(1))) void*)gA,
          (__attribute__((address_space(3))) void*)((char*)As + (wave * 2 + jj) * 1024),
          16, 0, 0);
      __builtin_amdgcn_global_load_lds(
          (__attribute__((address_space(1))) void*)gB,
          (__attribute__((address_space(3))) void*)((char*)Bs + (wave * 2 + jj) * 1024),
          16, 0, 0);
    }
    __syncthreads();

    v8bf a[4], b[4];
#pragma unroll
    for (int i = 0; i < 4; ++i)
      a[i] = *(const v8bf*)&As[(wr * 64 + i * 16 + r16) * 32 + sw * 8];
#pragma unroll
    for (int j = 0; j < 4; ++j)
      b[j] = *(const v8bf*)&Bs[(wc * 64 + j * 16 + r16) * 32 + sw * 8];
#pragma unroll
    for (int i = 0; i < 4; ++i)
#pragma unroll
      for (int j = 0; j < 4; ++j)
        acc[i][j] = __builtin_amdgcn_mfma_f32_16x16x32_bf16(a[i], b[j], acc[i][j], 0, 0, 0);
  }

  // Epilogue. C/D layout: col=lane&15, row=quad*4+reg (m89/m91-verified).
  const int mat = (int)blockIdx.x >> 3;
  const int ncol0 = ((int)blockIdx.x & 7) * 128;

  if (mat != 0) {
    unsigned short* Cm = (mat == 1) ? C1p : C2p;
#pragma unroll
    for (int i = 0; i < 4; ++i)
#pragma unroll
      for (int j = 0; j < 4; ++j)
#pragma unroll
        for (int r = 0; r < 4; ++r) {
          int row = mtile0 + wr * 64 + i * 16 + quad * 4 + r;
          int col = ncol0 + wc * 64 + j * 16 + r16;
          Cm[(size_t)row * HIDDEN + col] = f32_to_bf16(acc[i][j][r]);
        }
    return;
  }

  // mat==0: in-register inclusive cummax over each 32-row subchunk.
  // Wave owns rows wr*64 + i*16 + quad*4 + r; subchunk ih covers i=2ih,2ih+1.
  // Scan order per column (col = ncol0+wc*64+j*16+r16): r fastest, then quad
  // (stride-16 lanes, same r16), then i.
  const int bidx = mtile0 >> 12;
  const int sub0 = (mtile0 & 4095) >> 5;
#pragma unroll
  for (int ih = 0; ih < 2; ++ih) {
#pragma unroll
    for (int j = 0; j < 4; ++j) {
      float c0[4], c1[4];
      c0[0] = acc[ih * 2][j][0];
      c1[0] = acc[ih * 2 + 1][j][0];
#pragma unroll
      for (int r = 1; r < 4; ++r) {
        c0[r] = fmaxf(c0[r - 1], acc[ih * 2][j][r]);
        c1[r] = fmaxf(c1[r - 1], acc[ih * 2 + 1][j][r]);
      }
      float t0 = c0[3], t1 = c1[3], u;
      // inclusive Hillis-Steele over quads (lane stride 16, same column)
      u = __shfl_up(t0, 16); if (quad >= 1) t0 = fmaxf(t0, u);
      u = __shfl_up(t0, 32); if (quad >= 2) t0 = fmaxf(t0, u);
      u = __shfl_up(t1, 16); if (quad >= 1) t1 = fmaxf(t1, u);
      u = __shfl_up(t1, 32); if (quad >= 2) t1 = fmaxf(t1, u);
      float e0 = __shfl_up(t0, 16); if (quad == 0) e0 = -INFINITY;
      float e1 = __shfl_up(t1, 16); if (quad == 0) e1 = -INFINITY;
      float T0 = __shfl(t0, 48 + r16);   // full total of i=2ih half
      float T1 = __shfl(t1, 48 + r16);
      int col = ncol0 + wc * 64 + j * 16 + r16;
      int rowb = mtile0 + wr * 64 + ih * 32 + quad * 4;
#pragma unroll
      for (int r = 0; r < 4; ++r) {
        float L0 = fmaxf(c0[r], e0);
        float L1 = fmaxf(fmaxf(c1[r], e1), T0);
        Lp[(size_t)(rowb + r) * HIDDEN + col] = f32_to_bf16(L0);
        Lp[(size_t)(rowb + 16 + r) * HIDDEN + col] = f32_to_bf16(L1);
      }
      if (quad == 0) {
        int sub = sub0 + wr * 2 + ih;
        cmax[((size_t)bidx * NSUB + sub) * HIDDEN + col] = fmaxf(T0, T1);
      }
    }
  }
}

// ---- Exclusive prefix-max over subchunks (L2-resident, 2 MB) ----
// grid (4, 4): col = bx*256 + tid, b = by.  pmax[b][s] = max of cmax[b][<s]
__global__ void prefix_kernel(const float* __restrict__ cmax,
                              float* __restrict__ pmax) {
  int col = blockIdx.x * 256 + threadIdx.x;
  int b = blockIdx.y;
  const float* cp = cmax + (size_t)b * NSUB * HIDDEN + col;
  float* pp = pmax + (size_t)b * NSUB * HIDDEN + col;
  float run = -INFINITY;
#pragma unroll 4
  for (int s = 0; s < NSUB; ++s) {
    pp[(size_t)s * HIDDEN] = run;
    run = fmaxf(run, cp[(size_t)s * HIDDEN]);
  }
}

// ---- Final: pure elementwise, one row per block, perfectly balanced ----
// grid (4096, 4), block 256 (4 cols/thread).
__global__ void final_kernel(const unsigned short* __restrict__ L,
                             const unsigned short* __restrict__ C1,
                             const unsigned short* __restrict__ C2,
                             const float* __restrict__ pmax,
                             float* __restrict__ out) {
  const int col = threadIdx.x * 4;
  const int s = blockIdx.x;
  const int b = blockIdx.y;
  const int sub = s >> 5;
  float4 p = *(const float4*)(pmax + ((size_t)b * NSUB + sub) * HIDDEN + col);
  size_t base = ((size_t)b * SEQ + s) * HIDDEN + col;
  ushort4 ul = *(const ushort4*)(L + base);
  ushort4 u1 = *(const ushort4*)(C1 + base);
  ushort4 u2 = *(const ushort4*)(C2 + base);
  float m0 = fmaxf(p.x, bf16_to_f32(ul.x));
  float m1 = fmaxf(p.y, bf16_to_f32(ul.y));
  float m2 = fmaxf(p.z, bf16_to_f32(ul.z));
  float m3 = fmaxf(p.w, bf16_to_f32(ul.w));
  float4 o;
  o.x = (m0 + bf16_to_f32(u2.x)) * m0 + bf16_to_f32(u1.x);
  o.y = (m1 + bf16_to_f32(u2.y)) * m1 + bf16_to_f32(u1.y);
  o.z = (m2 + bf16_to_f32(u2.z)) * m2 + bf16_to_f32(u1.z);
  o.w = (m3 + bf16_to_f32(u2.w)) * m3 + bf16_to_f32(u1.w);
  *(float4*)(out + base) = o;
}

extern "C" void kernel_launch(void* const* d_in, const int* in_sizes, int n_in,
                              void* d_out, int out_size, void* d_ws, size_t ws_size,
                              hipStream_t stream) {
  const float* X = (const float*)d_in[0];
  const float* W0 = (const float*)d_in[1];
  const float* W1 = (const float*)d_in[2];
  const float* W2 = (const float*)d_in[3];
  float* out = (float*)d_out;

  // Workspace (~144.7 MiB):
  //   Xb   bf16 [16384][1024]   33,554,432 B
  //   Wb   bf16 [3072][1024]     6,291,456 B
  //   Lp   bf16 [16384][1024]   33,554,432 B   (in-subchunk cummax of S)
  //   C1p  bf16 [16384][1024]   33,554,432 B
  //   C2p  bf16 [16384][1024]   33,554,432 B
  //   cmax fp32 [4][128][1024]   2,097,152 B
  //   pmax fp32 [4][128][1024]   2,097,152 B
  char* ws = (char*)d_ws;
  unsigned short* Xb = (unsigned short*)ws;
  unsigned short* Wb = (unsigned short*)(ws + 33554432);
  unsigned short* Lp = (unsigned short*)(ws + 33554432 + 6291456);
  unsigned short* C1p = (unsigned short*)(ws + 2 * 33554432 + 6291456);
  unsigned short* C2p = (unsigned short*)(ws + 3 * 33554432 + 6291456);
  float* cmax = (float*)(ws + 4 * 33554432 + 6291456);
  float* pmax = (float*)(ws + 4 * 33554432 + 6291456 + 2097152);

  convert_kernel<<<19456, 256, 0, stream>>>(X, W0, W1, W2, Xb, Wb);

  dim3 ggrid(24, 128);  // n-tiles x m-tiles
  gemm_bt_kernel<<<ggrid, 256, 0, stream>>>((const bf16_t*)Xb, (const bf16_t*)Wb,
                                            Lp, C1p, C2p, cmax);

  dim3 pgrid(4, BATCH);
  prefix_kernel<<<pgrid, 256, 0, stream>>>(cmax, pmax);

  dim3 fgrid(SEQ, BATCH);
  final_kernel<<<fgrid, 256, 0, stream>>>(Lp, C1p, C2p, pmax, out);
}